// Round 2
// baseline (253.449 us; speedup 1.0000x reference)
//
#include <hip/hip_runtime.h>
#include <hip/hip_cooperative_groups.h>

namespace cg = cooperative_groups;

// B=64, IMG=1024, IND=64, E=4, FF=16. Inputs fp32, output fp32.
// Validated algebra (prior session, absmax 0.0): scalar token iv through
// affine stem -> softmax weight exp(a_r * x_t) with a_r = 0.5*(c1*iv_r + c0)
// (row const cancels); attention out = HB*rho + HC, rho = S1/S0.
// exp(z) Taylor K=12 (|z| <~ 1, rel err ~4e-10); S0,S1 are 13-term
// polynomials in a with per-batch moments M_k = sum_t x^k (f64 accumulation,
// summation order bit-identical to the 134.3us two-kernel winner).
//
// Round 11: single COOPERATIVE launch, 320 blocks x 256 thr (same parallelism
// as the winner -- round 10's 64x1024 fusion serialized 5 CUs of work onto 1
// CU and regressed). grid.sync() replaces the finalize kernel + its launch/
// dependency bubble. Tokens kept in registers (no iv[] LDS stage).
#define B_    64
#define IMG_  1024
#define IND_  64
#define NTHR  256
#define NBLK_IMG (B_ * 4)          // 4 blocks/batch, 256 rows each
#define NBLK  (NBLK_IMG + B_)      // 320

enum {
  W_IN = 0, B_IN = 4, QKV_W = 8, QKV_B = 56, O_W = 68, O_B = 84,
  LN1G = 88, LN1B = 92, FF1W = 96, FF1B = 160, FF2W = 176, FF2B = 240,
  LN2G = 244, LN2B = 248, W_OUT = 252, B_OUT = 256, WTOT = 257
};

struct KArgs {
  const float* in[36];
  float* pout;         // [NBLK][3] classifier partials (d_ws)
  float* out;          // [B_][3] (d_out)
};

__device__ __forceinline__ void stage(float* dst, const float* src, int n, int tid) {
  for (int i = tid; i < n; i += NTHR) dst[i] = src[i];
}

__device__ __forceinline__ double wave_sum_d(double v) {
  v += __shfl_xor(v, 1);  v += __shfl_xor(v, 2);  v += __shfl_xor(v, 4);
  v += __shfl_xor(v, 8);  v += __shfl_xor(v, 16); v += __shfl_xor(v, 32);
  return v;
}

// Per-row tail: derived affine constants (uniform, recomputed per thread),
// polynomial softmax sums, LN1 -> FF -> LN2 -> out-projection.
__device__ __forceinline__ float row_tail(const float* __restrict__ w,
                                          float ivr, const float* __restrict__ Mf) {
  float qd[4], qb[4], kd[4], vd[4], vb[4];
#pragma unroll
  for (int j = 0; j < 4; j++) {
    float a0 = 0.f, a1 = 0.f, a2 = 0.f, b0 = 0.f, b2 = 0.f;
#pragma unroll
    for (int e = 0; e < 4; e++) {
      const float we = w[W_IN + e], be = w[B_IN + e];
      a0 += we * w[QKV_W + e * 12 + j];      b0 += be * w[QKV_W + e * 12 + j];
      a1 += we * w[QKV_W + e * 12 + 4 + j];
      a2 += we * w[QKV_W + e * 12 + 8 + j];  b2 += be * w[QKV_W + e * 12 + 8 + j];
    }
    qd[j] = a0; qb[j] = b0 + w[QKV_B + j];
    kd[j] = a1;
    vd[j] = a2; vb[j] = b2 + w[QKV_B + 8 + j];
  }
  float c1 = 0.f, c0 = 0.f;
#pragma unroll
  for (int j = 0; j < 4; j++) { c1 += qd[j] * kd[j]; c0 += qb[j] * kd[j]; }
  float HB[4], HC[4];
#pragma unroll
  for (int j = 0; j < 4; j++) {
    float s1 = 0.f, s2 = 0.f;
#pragma unroll
    for (int f = 0; f < 4; f++) {
      s1 += vd[f] * w[O_W + f * 4 + j];
      s2 += vb[f] * w[O_W + f * 4 + j];
    }
    HB[j] = s1; HC[j] = w[B_IN + j] + s2 + w[O_B + j];
  }

  const float a = 0.5f * (c1 * ivr + c0);      // natural-exp coefficient
  float t = 1.f, S0 = Mf[0], S1 = Mf[1];
#pragma unroll
  for (int k = 1; k <= 12; k++) {
    t *= a * (1.0f / (float)k);
    S0 = fmaf(t, Mf[k], S0);
    S1 = fmaf(t, Mf[k + 1], S1);
  }
  const float rho = S1 / S0;

  float h[4];
#pragma unroll
  for (int j = 0; j < 4; j++) h[j] = w[W_IN + j] * ivr + HB[j] * rho + HC[j];
  {
    const float mn = 0.25f * (h[0] + h[1] + h[2] + h[3]);
    float v = 0.f;
#pragma unroll
    for (int j = 0; j < 4; j++) { const float d = h[j] - mn; v += d * d; }
    const float rs = rsqrtf(v * 0.25f + 1e-5f);
#pragma unroll
    for (int j = 0; j < 4; j++) h[j] = (h[j] - mn) * rs * w[LN1G + j] + w[LN1B + j];
  }
  float f2[4] = {w[FF2B + 0], w[FF2B + 1], w[FF2B + 2], w[FF2B + 3]};
#pragma unroll
  for (int tt = 0; tt < 16; tt++) {
    float u = w[FF1B + tt];
#pragma unroll
    for (int j = 0; j < 4; j++) u += h[j] * w[FF1W + j * 16 + tt];
    u = fmaxf(u, 0.f);
#pragma unroll
    for (int j = 0; j < 4; j++) f2[j] += u * w[FF2W + tt * 4 + j];
  }
  float h2[4];
#pragma unroll
  for (int j = 0; j < 4; j++) h2[j] = h[j] + f2[j];
  {
    const float mn = 0.25f * (h2[0] + h2[1] + h2[2] + h2[3]);
    float v = 0.f;
#pragma unroll
    for (int j = 0; j < 4; j++) { const float d = h2[j] - mn; v += d * d; }
    const float rs = rsqrtf(v * 0.25f + 1e-5f);
#pragma unroll
    for (int j = 0; j < 4; j++) h2[j] = (h2[j] - mn) * rs * w[LN2G + j] + w[LN2B + j];
  }
  float outv = w[B_OUT];
#pragma unroll
  for (int j = 0; j < 4; j++) outv += h2[j] * w[W_OUT + j];
  return outv;
}

__global__ __launch_bounds__(NTHR) void fused(KArgs A) {
  const int blk = blockIdx.x;
  const int tid = threadIdx.x;
  const bool is_img = blk < NBLK_IMG;

  __shared__ float w[WTOT];
  __shared__ double mws[4][13];
  __shared__ float red[4][3];

  int batch, tb;
  const float* xin;
  if (is_img) {
    batch = blk >> 2; xin = A.in[0] + batch * IMG_; tb = 10;
  } else {
    batch = blk - NBLK_IMG; xin = A.in[1] + batch * IND_; tb = 22;
  }

  // ---- stage weights ----
  stage(w + W_IN,  A.in[is_img ? 2 : 4], 4,  tid);
  stage(w + B_IN,  A.in[is_img ? 3 : 5], 4,  tid);
  stage(w + W_OUT, A.in[is_img ? 6 : 8], 4,  tid);
  stage(w + B_OUT, A.in[is_img ? 7 : 9], 1,  tid);
  stage(w + QKV_W, A.in[tb + 0], 48, tid);
  stage(w + QKV_B, A.in[tb + 1], 12, tid);
  stage(w + O_W,   A.in[tb + 2], 16, tid);
  stage(w + O_B,   A.in[tb + 3], 4,  tid);
  stage(w + LN1G,  A.in[tb + 4], 4,  tid);
  stage(w + LN1B,  A.in[tb + 5], 4,  tid);
  stage(w + FF1W,  A.in[tb + 6], 64, tid);
  stage(w + FF1B,  A.in[tb + 7], 16, tid);
  stage(w + FF2W,  A.in[tb + 8], 64, tid);
  stage(w + FF2B,  A.in[tb + 9], 4,  tid);
  stage(w + LN2G,  A.in[tb + 10], 4, tid);
  stage(w + LN2B,  A.in[tb + 11], 4, tid);

  // ---- tokens straight to registers (no LDS stage) ----
  float tok[4];
  if (is_img) {
#pragma unroll
    for (int q = 0; q < 4; q++) tok[q] = xin[tid + 256 * q];
  } else {
    tok[0] = (tid < IND_) ? xin[tid] : 0.f;
    tok[1] = tok[2] = tok[3] = 0.f;
  }
  __syncthreads();

  // ---- per-batch moments M_1..M_13 (f64, order identical to winner) ----
  double m[13];
#pragma unroll
  for (int k = 0; k < 13; k++) m[k] = 0.0;
  if (is_img) {
#pragma unroll
    for (int q = 0; q < 4; q++) {            // tokens tid, tid+256, tid+512, tid+768
      const double x = (double)tok[q];
      double px = x;
#pragma unroll
      for (int k = 0; k < 13; k++) { m[k] += px; px *= x; }
    }
  } else {
    const double x = (double)tok[0];         // 0 for tid>=64 -> contributes 0
    double px = x;
#pragma unroll
    for (int k = 0; k < 13; k++) { m[k] += px; px *= x; }
  }
#pragma unroll
  for (int k = 0; k < 13; k++) m[k] = wave_sum_d(m[k]);
  if ((tid & 63) == 0) {
    const int wv = tid >> 6;
#pragma unroll
    for (int k = 0; k < 13; k++) mws[wv][k] = m[k];
  }
  __syncthreads();
  float Mf[14];
  Mf[0] = (float)(is_img ? IMG_ : IND_);
#pragma unroll
  for (int k = 0; k < 13; k++)
    Mf[k + 1] = (float)(mws[0][k] + mws[1][k] + mws[2][k] + mws[3][k]);

  // ---- one row per thread: tail + classifier partials ----
  const bool active = is_img || (tid < IND_);
  const int q = blk & 3;
  const float ivr = is_img ? tok[q] : tok[0];
  float p0 = 0.f, p1 = 0.f, p2 = 0.f;
  if (active) {
    const float outv = row_tail(w, ivr, Mf);
    const int g = is_img ? (q * 256 + tid) : (IMG_ + tid);
    const float* wc = A.in[34] + 3 * g;
    p0 = outv * wc[0]; p1 = outv * wc[1]; p2 = outv * wc[2];
  }
#pragma unroll
  for (int msk = 1; msk < 64; msk <<= 1) {
    p0 += __shfl_xor(p0, msk); p1 += __shfl_xor(p1, msk); p2 += __shfl_xor(p2, msk);
  }
  if ((tid & 63) == 0) {
    const int wv = tid >> 6;
    red[wv][0] = p0; red[wv][1] = p1; red[wv][2] = p2;
  }
  __syncthreads();
  if (tid == 0) {
    A.pout[blk * 3 + 0] = red[0][0] + red[1][0] + red[2][0] + red[3][0];
    A.pout[blk * 3 + 1] = red[0][1] + red[1][1] + red[2][1] + red[3][1];
    A.pout[blk * 3 + 2] = red[0][2] + red[1][2] + red[2][2] + red[3][2];
  }

  // ---- grid-wide sync, then blocks 0..63 finalize one batch each ----
  __threadfence();
  cg::this_grid().sync();

  if (blk < B_ && tid == 0) {
    const float* bc = A.in[35];
    float z[3];
#pragma unroll
    for (int c = 0; c < 3; c++) {
      float s = bc[c];
#pragma unroll
      for (int i = 0; i < 4; i++) s += A.pout[(4 * blk + i) * 3 + c];
      s += A.pout[(NBLK_IMG + blk) * 3 + c];
      z[c] = s;
    }
    const float mx = fmaxf(z[0], fmaxf(z[1], z[2]));
    const float e0 = __expf(z[0] - mx), e1 = __expf(z[1] - mx), e2 = __expf(z[2] - mx);
    const float rs = 1.f / (e0 + e1 + e2);
    A.out[blk * 3 + 0] = e0 * rs;
    A.out[blk * 3 + 1] = e1 * rs;
    A.out[blk * 3 + 2] = e2 * rs;
  }
}

extern "C" void kernel_launch(void* const* d_in, const int* in_sizes, int n_in,
                              void* d_out, int out_size, void* d_ws, size_t ws_size,
                              hipStream_t stream) {
  KArgs A;
  for (int i = 0; i < 36; i++) A.in[i] = (const float*)d_in[i];
  A.pout = (float*)d_ws;          // NBLK*3 floats, fully overwritten each call
  A.out  = (float*)d_out;

  void* args[] = {(void*)&A};
  hipLaunchCooperativeKernel((void*)fused, dim3(NBLK), dim3(NTHR), args, 0, stream);
}

// Round 3
// 141.534 us; speedup vs baseline: 1.7907x; 1.7907x over previous
//
#include <hip/hip_runtime.h>

// B=64, IMG=1024, IND=64, E=4, FF=16. Inputs fp32, output fp32.
// Validated algebra (prior session, absmax 0.0): scalar token iv through
// affine stem -> softmax weight exp(a_r * x_t) with a_r = 0.5*(c1*iv_r + c0)
// (row const cancels); attention out = HB*rho + HC, rho = S1/S0.
// exp(z) Taylor K=12 (|z| <~ 1, rel err ~4e-10); S0,S1 are 13-term
// polynomials in a with per-batch moments M_k = sum_t x^k (f64 accumulation).
//
// Round 12: two-phase winner structure (320 blocks x 256 thr) but ONE kernel:
// last-arriving block (device-scope atomic ticket, counter zeroed by a 4-byte
// hipMemsetAsync) runs the finalize with its first 64 threads. No grid.sync
// (round 11: 78us barrier cost), no second launch + dependency gap (~6-10us).
// Tokens in registers (no iv[] LDS stage); f64 moment order unchanged.
#define B_    64
#define IMG_  1024
#define IND_  64
#define NTHR  256
#define NBLK_IMG (B_ * 4)          // 4 blocks/batch, 256 rows each
#define NBLK  (NBLK_IMG + B_)      // 320
#define CNT_IDX (NBLK * 3)         // counter slot in d_ws, after partials

enum {
  W_IN = 0, B_IN = 4, QKV_W = 8, QKV_B = 56, O_W = 68, O_B = 84,
  LN1G = 88, LN1B = 92, FF1W = 96, FF1B = 160, FF2W = 176, FF2B = 240,
  LN2G = 244, LN2B = 248, W_OUT = 252, B_OUT = 256, WTOT = 257
};

struct KArgs {
  const float* in[36];
  float* pout;          // [NBLK][3] classifier partials (d_ws)
  unsigned int* cnt;    // ticket counter (d_ws, zeroed pre-launch)
  float* out;           // [B_][3] (d_out)
};

__device__ __forceinline__ void stage(float* dst, const float* src, int n, int tid) {
  for (int i = tid; i < n; i += NTHR) dst[i] = src[i];
}

__device__ __forceinline__ double wave_sum_d(double v) {
  v += __shfl_xor(v, 1);  v += __shfl_xor(v, 2);  v += __shfl_xor(v, 4);
  v += __shfl_xor(v, 8);  v += __shfl_xor(v, 16); v += __shfl_xor(v, 32);
  return v;
}

// Per-row tail: derived affine constants (uniform, recomputed per thread),
// polynomial softmax sums, LN1 -> FF -> LN2 -> out-projection.
__device__ __forceinline__ float row_tail(const float* __restrict__ w,
                                          float ivr, const float* __restrict__ Mf) {
  float qd[4], qb[4], kd[4], vd[4], vb[4];
#pragma unroll
  for (int j = 0; j < 4; j++) {
    float a0 = 0.f, a1 = 0.f, a2 = 0.f, b0 = 0.f, b2 = 0.f;
#pragma unroll
    for (int e = 0; e < 4; e++) {
      const float we = w[W_IN + e], be = w[B_IN + e];
      a0 += we * w[QKV_W + e * 12 + j];      b0 += be * w[QKV_W + e * 12 + j];
      a1 += we * w[QKV_W + e * 12 + 4 + j];
      a2 += we * w[QKV_W + e * 12 + 8 + j];  b2 += be * w[QKV_W + e * 12 + 8 + j];
    }
    qd[j] = a0; qb[j] = b0 + w[QKV_B + j];
    kd[j] = a1;
    vd[j] = a2; vb[j] = b2 + w[QKV_B + 8 + j];
  }
  float c1 = 0.f, c0 = 0.f;
#pragma unroll
  for (int j = 0; j < 4; j++) { c1 += qd[j] * kd[j]; c0 += qb[j] * kd[j]; }
  float HB[4], HC[4];
#pragma unroll
  for (int j = 0; j < 4; j++) {
    float s1 = 0.f, s2 = 0.f;
#pragma unroll
    for (int f = 0; f < 4; f++) {
      s1 += vd[f] * w[O_W + f * 4 + j];
      s2 += vb[f] * w[O_W + f * 4 + j];
    }
    HB[j] = s1; HC[j] = w[B_IN + j] + s2 + w[O_B + j];
  }

  const float a = 0.5f * (c1 * ivr + c0);      // natural-exp coefficient
  float t = 1.f, S0 = Mf[0], S1 = Mf[1];
#pragma unroll
  for (int k = 1; k <= 12; k++) {
    t *= a * (1.0f / (float)k);
    S0 = fmaf(t, Mf[k], S0);
    S1 = fmaf(t, Mf[k + 1], S1);
  }
  const float rho = S1 / S0;

  float h[4];
#pragma unroll
  for (int j = 0; j < 4; j++) h[j] = w[W_IN + j] * ivr + HB[j] * rho + HC[j];
  {
    const float mn = 0.25f * (h[0] + h[1] + h[2] + h[3]);
    float v = 0.f;
#pragma unroll
    for (int j = 0; j < 4; j++) { const float d = h[j] - mn; v += d * d; }
    const float rs = rsqrtf(v * 0.25f + 1e-5f);
#pragma unroll
    for (int j = 0; j < 4; j++) h[j] = (h[j] - mn) * rs * w[LN1G + j] + w[LN1B + j];
  }
  float f2[4] = {w[FF2B + 0], w[FF2B + 1], w[FF2B + 2], w[FF2B + 3]};
#pragma unroll
  for (int tt = 0; tt < 16; tt++) {
    float u = w[FF1B + tt];
#pragma unroll
    for (int j = 0; j < 4; j++) u += h[j] * w[FF1W + j * 16 + tt];
    u = fmaxf(u, 0.f);
#pragma unroll
    for (int j = 0; j < 4; j++) f2[j] += u * w[FF2W + tt * 4 + j];
  }
  float h2[4];
#pragma unroll
  for (int j = 0; j < 4; j++) h2[j] = h[j] + f2[j];
  {
    const float mn = 0.25f * (h2[0] + h2[1] + h2[2] + h2[3]);
    float v = 0.f;
#pragma unroll
    for (int j = 0; j < 4; j++) { const float d = h2[j] - mn; v += d * d; }
    const float rs = rsqrtf(v * 0.25f + 1e-5f);
#pragma unroll
    for (int j = 0; j < 4; j++) h2[j] = (h2[j] - mn) * rs * w[LN2G + j] + w[LN2B + j];
  }
  float outv = w[B_OUT];
#pragma unroll
  for (int j = 0; j < 4; j++) outv += h2[j] * w[W_OUT + j];
  return outv;
}

__global__ __launch_bounds__(NTHR) void fused(KArgs A) {
  const int blk = blockIdx.x;
  const int tid = threadIdx.x;
  const bool is_img = blk < NBLK_IMG;

  __shared__ float w[WTOT];
  __shared__ double mws[4][13];
  __shared__ float red[4][3];
  __shared__ int is_last;

  int batch, tb;
  const float* xin;
  if (is_img) {
    batch = blk >> 2; xin = A.in[0] + batch * IMG_; tb = 10;
  } else {
    batch = blk - NBLK_IMG; xin = A.in[1] + batch * IND_; tb = 22;
  }

  // ---- stage weights ----
  stage(w + W_IN,  A.in[is_img ? 2 : 4], 4,  tid);
  stage(w + B_IN,  A.in[is_img ? 3 : 5], 4,  tid);
  stage(w + W_OUT, A.in[is_img ? 6 : 8], 4,  tid);
  stage(w + B_OUT, A.in[is_img ? 7 : 9], 1,  tid);
  stage(w + QKV_W, A.in[tb + 0], 48, tid);
  stage(w + QKV_B, A.in[tb + 1], 12, tid);
  stage(w + O_W,   A.in[tb + 2], 16, tid);
  stage(w + O_B,   A.in[tb + 3], 4,  tid);
  stage(w + LN1G,  A.in[tb + 4], 4,  tid);
  stage(w + LN1B,  A.in[tb + 5], 4,  tid);
  stage(w + FF1W,  A.in[tb + 6], 64, tid);
  stage(w + FF1B,  A.in[tb + 7], 16, tid);
  stage(w + FF2W,  A.in[tb + 8], 64, tid);
  stage(w + FF2B,  A.in[tb + 9], 4,  tid);
  stage(w + LN2G,  A.in[tb + 10], 4, tid);
  stage(w + LN2B,  A.in[tb + 11], 4, tid);

  // ---- tokens straight to registers (no LDS stage) ----
  float tok[4];
  if (is_img) {
#pragma unroll
    for (int q = 0; q < 4; q++) tok[q] = xin[tid + 256 * q];
  } else {
    tok[0] = (tid < IND_) ? xin[tid] : 0.f;
    tok[1] = tok[2] = tok[3] = 0.f;
  }
  __syncthreads();

  // ---- per-batch moments M_1..M_13 (f64, order identical to winner) ----
  double m[13];
#pragma unroll
  for (int k = 0; k < 13; k++) m[k] = 0.0;
  if (is_img) {
#pragma unroll
    for (int q = 0; q < 4; q++) {            // tokens tid, tid+256, tid+512, tid+768
      const double x = (double)tok[q];
      double px = x;
#pragma unroll
      for (int k = 0; k < 13; k++) { m[k] += px; px *= x; }
    }
  } else {
    const double x = (double)tok[0];         // 0 for tid>=64 -> contributes 0
    double px = x;
#pragma unroll
    for (int k = 0; k < 13; k++) { m[k] += px; px *= x; }
  }
#pragma unroll
  for (int k = 0; k < 13; k++) m[k] = wave_sum_d(m[k]);
  if ((tid & 63) == 0) {
    const int wv = tid >> 6;
#pragma unroll
    for (int k = 0; k < 13; k++) mws[wv][k] = m[k];
  }
  __syncthreads();
  float Mf[14];
  Mf[0] = (float)(is_img ? IMG_ : IND_);
#pragma unroll
  for (int k = 0; k < 13; k++)
    Mf[k + 1] = (float)(mws[0][k] + mws[1][k] + mws[2][k] + mws[3][k]);

  // ---- one row per thread: tail + classifier partials ----
  const bool active = is_img || (tid < IND_);
  const int q = blk & 3;
  const float ivr = is_img ? tok[q] : tok[0];
  float p0 = 0.f, p1 = 0.f, p2 = 0.f;
  if (active) {
    const float outv = row_tail(w, ivr, Mf);
    const int g = is_img ? (q * 256 + tid) : (IMG_ + tid);
    const float* wc = A.in[34] + 3 * g;
    p0 = outv * wc[0]; p1 = outv * wc[1]; p2 = outv * wc[2];
  }
#pragma unroll
  for (int msk = 1; msk < 64; msk <<= 1) {
    p0 += __shfl_xor(p0, msk); p1 += __shfl_xor(p1, msk); p2 += __shfl_xor(p2, msk);
  }
  if ((tid & 63) == 0) {
    const int wv = tid >> 6;
    red[wv][0] = p0; red[wv][1] = p1; red[wv][2] = p2;
  }
  __syncthreads();

  // ---- publish partials (agent scope), take a ticket; last block finalizes ----
  if (tid == 0) {
    const float s0 = red[0][0] + red[1][0] + red[2][0] + red[3][0];
    const float s1 = red[0][1] + red[1][1] + red[2][1] + red[3][1];
    const float s2 = red[0][2] + red[1][2] + red[2][2] + red[3][2];
    __hip_atomic_store(&A.pout[blk * 3 + 0], s0, __ATOMIC_RELAXED, __HIP_MEMORY_SCOPE_AGENT);
    __hip_atomic_store(&A.pout[blk * 3 + 1], s1, __ATOMIC_RELAXED, __HIP_MEMORY_SCOPE_AGENT);
    __hip_atomic_store(&A.pout[blk * 3 + 2], s2, __ATOMIC_RELAXED, __HIP_MEMORY_SCOPE_AGENT);
    const unsigned int old =
        __hip_atomic_fetch_add(A.cnt, 1u, __ATOMIC_ACQ_REL, __HIP_MEMORY_SCOPE_AGENT);
    is_last = (old == NBLK - 1);
  }
  __syncthreads();

  if (is_last && tid < B_) {
    const int b = tid;   // one thread per batch
    const float* bc = A.in[35];
    float z[3];
#pragma unroll
    for (int c = 0; c < 3; c++) {
      float s = bc[c];
#pragma unroll
      for (int i = 0; i < 4; i++)
        s += __hip_atomic_load(&A.pout[(4 * b + i) * 3 + c],
                               __ATOMIC_RELAXED, __HIP_MEMORY_SCOPE_AGENT);
      s += __hip_atomic_load(&A.pout[(NBLK_IMG + b) * 3 + c],
                             __ATOMIC_RELAXED, __HIP_MEMORY_SCOPE_AGENT);
      z[c] = s;
    }
    const float mx = fmaxf(z[0], fmaxf(z[1], z[2]));
    const float e0 = __expf(z[0] - mx), e1 = __expf(z[1] - mx), e2 = __expf(z[2] - mx);
    const float rs = 1.f / (e0 + e1 + e2);
    A.out[b * 3 + 0] = e0 * rs;
    A.out[b * 3 + 1] = e1 * rs;
    A.out[b * 3 + 2] = e2 * rs;
  }
}

extern "C" void kernel_launch(void* const* d_in, const int* in_sizes, int n_in,
                              void* d_out, int out_size, void* d_ws, size_t ws_size,
                              hipStream_t stream) {
  KArgs A;
  for (int i = 0; i < 36; i++) A.in[i] = (const float*)d_in[i];
  A.pout = (float*)d_ws;                       // NBLK*3 floats
  A.cnt  = (unsigned int*)d_ws + CNT_IDX;      // ticket counter
  A.out  = (float*)d_out;

  hipMemsetAsync(A.cnt, 0, sizeof(unsigned int), stream);
  fused<<<NBLK, NTHR, 0, stream>>>(A);
}

// Round 5
// 131.459 us; speedup vs baseline: 1.9280x; 1.0766x over previous
//
#include <hip/hip_runtime.h>

// B=64, IMG=1024, IND=64, E=4, FF=16. Inputs fp32, output fp32.
// Validated algebra (prior session, absmax 0.0): scalar token iv through
// affine stem -> softmax weight exp(a_r * x_t) with a_r = 0.5*(c1*iv_r + c0)
// (row const cancels); attention out = HB*rho + HC, rho = S1/S0.
// exp(z) Taylor K=12 (|z| <~ 1, rel err ~4e-10); S0,S1 are 13-term
// polynomials in a with per-batch moments M_k = sum_t x^k (f64 accumulation,
// identical summation order to the 134.3us two-kernel winner; register-token
// variant verified absmax 0.0 in round 3).
//
// Round 14: ONE dispatch, hang-proof. Img block (b,q) publishes its 3
// classifier partials as self-validating u64 (bits(v) | ~bits(v)<<32) via
// relaxed agent-scope atomics -- ws poison is a repeated 32-bit pattern so
// hi==~lo is unsatisfiable for poison, no init/memset/ticket needed.
// Ind block b (IDs 256..319) finalizes its batch: 12 lanes poll the 4x3
// slots with a BOUNDED spin (65536 tries + s_sleep). On timeout it falls
// back to recomputing the four img partials itself, bit-identically (same
// token->thread mapping, same f64 moment order, same butterfly, same red[]
// sum order, re-staged t1 weights) -- so a visibility/residency failure
// degrades to slow-but-correct instead of hanging the container.
#define B_    64
#define IMG_  1024
#define IND_  64
#define NTHR  256
#define NBLK_IMG (B_ * 4)          // 4 img blocks/batch, 256 rows each
#define NBLK  (NBLK_IMG + B_)      // 320
#define SPIN_MAX 65536

enum {
  W_IN = 0, B_IN = 4, QKV_W = 8, QKV_B = 56, O_W = 68, O_B = 84,
  LN1G = 88, LN1B = 92, FF1W = 96, FF1B = 160, FF2W = 176, FF2B = 240,
  LN2G = 244, LN2B = 248, W_OUT = 252, B_OUT = 256, WTOT = 257
};

struct KArgs {
  const float* in[36];
  unsigned long long* pout;  // [B_][4][3] packed self-validating partials (d_ws)
  float* out;                // [B_][3] (d_out)
};

__device__ __forceinline__ void stage(float* dst, const float* src, int n, int tid) {
  for (int i = tid; i < n; i += NTHR) dst[i] = src[i];
}

__device__ __forceinline__ double wave_sum_d(double v) {
  v += __shfl_xor(v, 1);  v += __shfl_xor(v, 2);  v += __shfl_xor(v, 4);
  v += __shfl_xor(v, 8);  v += __shfl_xor(v, 16); v += __shfl_xor(v, 32);
  return v;
}

// Per-row tail: derived affine constants (uniform, recomputed per thread),
// polynomial softmax sums, LN1 -> FF -> LN2 -> out-projection.
__device__ __forceinline__ float row_tail(const float* __restrict__ w,
                                          float ivr, const float* __restrict__ Mf) {
  float qd[4], qb[4], kd[4], vd[4], vb[4];
#pragma unroll
  for (int j = 0; j < 4; j++) {
    float a0 = 0.f, a1 = 0.f, a2 = 0.f, b0 = 0.f, b2 = 0.f;
#pragma unroll
    for (int e = 0; e < 4; e++) {
      const float we = w[W_IN + e], be = w[B_IN + e];
      a0 += we * w[QKV_W + e * 12 + j];      b0 += be * w[QKV_W + e * 12 + j];
      a1 += we * w[QKV_W + e * 12 + 4 + j];
      a2 += we * w[QKV_W + e * 12 + 8 + j];  b2 += be * w[QKV_W + e * 12 + 8 + j];
    }
    qd[j] = a0; qb[j] = b0 + w[QKV_B + j];
    kd[j] = a1;
    vd[j] = a2; vb[j] = b2 + w[QKV_B + 8 + j];
  }
  float c1 = 0.f, c0 = 0.f;
#pragma unroll
  for (int j = 0; j < 4; j++) { c1 += qd[j] * kd[j]; c0 += qb[j] * kd[j]; }
  float HB[4], HC[4];
#pragma unroll
  for (int j = 0; j < 4; j++) {
    float s1 = 0.f, s2 = 0.f;
#pragma unroll
    for (int f = 0; f < 4; f++) {
      s1 += vd[f] * w[O_W + f * 4 + j];
      s2 += vb[f] * w[O_W + f * 4 + j];
    }
    HB[j] = s1; HC[j] = w[B_IN + j] + s2 + w[O_B + j];
  }

  const float a = 0.5f * (c1 * ivr + c0);      // natural-exp coefficient
  float t = 1.f, S0 = Mf[0], S1 = Mf[1];
#pragma unroll
  for (int k = 1; k <= 12; k++) {
    t *= a * (1.0f / (float)k);
    S0 = fmaf(t, Mf[k], S0);
    S1 = fmaf(t, Mf[k + 1], S1);
  }
  const float rho = S1 / S0;

  float h[4];
#pragma unroll
  for (int j = 0; j < 4; j++) h[j] = w[W_IN + j] * ivr + HB[j] * rho + HC[j];
  {
    const float mn = 0.25f * (h[0] + h[1] + h[2] + h[3]);
    float v = 0.f;
#pragma unroll
    for (int j = 0; j < 4; j++) { const float d = h[j] - mn; v += d * d; }
    const float rs = rsqrtf(v * 0.25f + 1e-5f);
#pragma unroll
    for (int j = 0; j < 4; j++) h[j] = (h[j] - mn) * rs * w[LN1G + j] + w[LN1B + j];
  }
  float f2[4] = {w[FF2B + 0], w[FF2B + 1], w[FF2B + 2], w[FF2B + 3]};
#pragma unroll
  for (int tt = 0; tt < 16; tt++) {
    float u = w[FF1B + tt];
#pragma unroll
    for (int j = 0; j < 4; j++) u += h[j] * w[FF1W + j * 16 + tt];
    u = fmaxf(u, 0.f);
#pragma unroll
    for (int j = 0; j < 4; j++) f2[j] += u * w[FF2W + tt * 4 + j];
  }
  float h2[4];
#pragma unroll
  for (int j = 0; j < 4; j++) h2[j] = h[j] + f2[j];
  {
    const float mn = 0.25f * (h2[0] + h2[1] + h2[2] + h2[3]);
    float v = 0.f;
#pragma unroll
    for (int j = 0; j < 4; j++) { const float d = h2[j] - mn; v += d * d; }
    const float rs = rsqrtf(v * 0.25f + 1e-5f);
#pragma unroll
    for (int j = 0; j < 4; j++) h2[j] = (h2[j] - mn) * rs * w[LN2G + j] + w[LN2B + j];
  }
  float outv = w[B_OUT];
#pragma unroll
  for (int j = 0; j < 4; j++) outv += h2[j] * w[W_OUT + j];
  return outv;
}

__device__ __forceinline__ unsigned long long pack_valid(float v) {
  const unsigned int lo = __float_as_uint(v);
  return (unsigned long long)lo | ((unsigned long long)(~lo) << 32);
}

__global__ __launch_bounds__(NTHR) void fused(KArgs A) {
  const int blk = blockIdx.x;
  const int tid = threadIdx.x;
  const bool is_img = blk < NBLK_IMG;

  __shared__ float w[WTOT];
  __shared__ double mws[4][13];
  __shared__ float red[4][3];
  __shared__ float vals[12];
  __shared__ int okflag;

  int batch, tb;
  const float* xin;
  if (is_img) {
    batch = blk >> 2; xin = A.in[0] + batch * IMG_; tb = 10;
  } else {
    batch = blk - NBLK_IMG; xin = A.in[1] + batch * IND_; tb = 22;
  }

  // ---- stage weights (barrier deferred: moments touch no LDS weights) ----
  stage(w + W_IN,  A.in[is_img ? 2 : 4], 4,  tid);
  stage(w + B_IN,  A.in[is_img ? 3 : 5], 4,  tid);
  stage(w + W_OUT, A.in[is_img ? 6 : 8], 4,  tid);
  stage(w + B_OUT, A.in[is_img ? 7 : 9], 1,  tid);
  stage(w + QKV_W, A.in[tb + 0], 48, tid);
  stage(w + QKV_B, A.in[tb + 1], 12, tid);
  stage(w + O_W,   A.in[tb + 2], 16, tid);
  stage(w + O_B,   A.in[tb + 3], 4,  tid);
  stage(w + LN1G,  A.in[tb + 4], 4,  tid);
  stage(w + LN1B,  A.in[tb + 5], 4,  tid);
  stage(w + FF1W,  A.in[tb + 6], 64, tid);
  stage(w + FF1B,  A.in[tb + 7], 16, tid);
  stage(w + FF2W,  A.in[tb + 8], 64, tid);
  stage(w + FF2B,  A.in[tb + 9], 4,  tid);
  stage(w + LN2G,  A.in[tb + 10], 4, tid);
  stage(w + LN2B,  A.in[tb + 11], 4, tid);

  // ---- tokens straight to registers ----
  float tok[4];
  if (is_img) {
#pragma unroll
    for (int q = 0; q < 4; q++) tok[q] = xin[tid + 256 * q];
  } else {
    tok[0] = (tid < IND_) ? xin[tid] : 0.f;
    tok[1] = tok[2] = tok[3] = 0.f;
  }

  // ---- per-batch moments M_1..M_13 (f64, order identical to winner) ----
  double m[13];
#pragma unroll
  for (int k = 0; k < 13; k++) m[k] = 0.0;
  if (is_img) {
#pragma unroll
    for (int q = 0; q < 4; q++) {            // tokens tid, tid+256, tid+512, tid+768
      const double x = (double)tok[q];
      double px = x;
#pragma unroll
      for (int k = 0; k < 13; k++) { m[k] += px; px *= x; }
    }
  } else {
    const double x = (double)tok[0];         // 0 for tid>=64 -> contributes 0
    double px = x;
#pragma unroll
    for (int k = 0; k < 13; k++) { m[k] += px; px *= x; }
  }
#pragma unroll
  for (int k = 0; k < 13; k++) m[k] = wave_sum_d(m[k]);
  if ((tid & 63) == 0) {
    const int wv = tid >> 6;
#pragma unroll
    for (int k = 0; k < 13; k++) mws[wv][k] = m[k];
  }
  __syncthreads();             // covers weight staging AND mws publication
  float Mf[14];
  Mf[0] = (float)(is_img ? IMG_ : IND_);
#pragma unroll
  for (int k = 0; k < 13; k++)
    Mf[k + 1] = (float)(mws[0][k] + mws[1][k] + mws[2][k] + mws[3][k]);

  // ---- one row per thread: tail + classifier partials ----
  const bool active = is_img || (tid < IND_);
  const int q = blk & 3;
  const float ivr = is_img ? tok[q] : tok[0];
  float p0 = 0.f, p1 = 0.f, p2 = 0.f;
  if (active) {
    const float outv = row_tail(w, ivr, Mf);
    const int g = is_img ? (q * 256 + tid) : (IMG_ + tid);
    const float* wc = A.in[34] + 3 * g;
    p0 = outv * wc[0]; p1 = outv * wc[1]; p2 = outv * wc[2];
  }
#pragma unroll
  for (int msk = 1; msk < 64; msk <<= 1) {
    p0 += __shfl_xor(p0, msk); p1 += __shfl_xor(p1, msk); p2 += __shfl_xor(p2, msk);
  }
  if ((tid & 63) == 0) {
    const int wv = tid >> 6;
    red[wv][0] = p0; red[wv][1] = p1; red[wv][2] = p2;
  }
  __syncthreads();

  if (is_img) {
    // ---- publish self-validating packed partials (relaxed agent atomics) ----
    if (tid == 0) {
      const float s0 = red[0][0] + red[1][0] + red[2][0] + red[3][0];
      const float s1 = red[0][1] + red[1][1] + red[2][1] + red[3][1];
      const float s2 = red[0][2] + red[1][2] + red[2][2] + red[3][2];
      unsigned long long* slot = A.pout + (unsigned long long)(batch * 12 + q * 3);
      __hip_atomic_store(&slot[0], pack_valid(s0), __ATOMIC_RELAXED, __HIP_MEMORY_SCOPE_AGENT);
      __hip_atomic_store(&slot[1], pack_valid(s1), __ATOMIC_RELAXED, __HIP_MEMORY_SCOPE_AGENT);
      __hip_atomic_store(&slot[2], pack_valid(s2), __ATOMIC_RELAXED, __HIP_MEMORY_SCOPE_AGENT);
    }
    return;
  }

  // ---- ind block = per-batch finalizer ----
  // own ind partial (every thread computes the same sums from red)
  const float si0 = red[0][0] + red[1][0] + red[2][0] + red[3][0];
  const float si1 = red[0][1] + red[1][1] + red[2][1] + red[3][1];
  const float si2 = red[0][2] + red[1][2] + red[2][2] + red[3][2];

  // bounded poll of the 4x3 img slots (12 lanes of wave 0)
  bool got = false;
  if (tid < 12) {
    unsigned long long* slot = A.pout + (unsigned long long)(batch * 12 + tid);
    for (int it = 0; it < SPIN_MAX; ++it) {
      const unsigned long long v =
          __hip_atomic_load(slot, __ATOMIC_RELAXED, __HIP_MEMORY_SCOPE_AGENT);
      if ((unsigned int)(v >> 32) == ~(unsigned int)v) {    // poison has hi==lo
        vals[tid] = __uint_as_float((unsigned int)v);
        got = true;
        break;
      }
      __builtin_amdgcn_s_sleep(1);
    }
  }
  const unsigned long long bal = __ballot(got);
  if (tid == 0) okflag = ((bal & 0xFFFull) == 0xFFFull);
  __syncthreads();

  float sq[4][3];                 // fallback img partials (bit-identical path)
  const bool fb = !okflag;
  if (fb) {
    // re-stage t1 weights (everyone is done reading the t2 set)
    stage(w + W_IN,  A.in[2], 4,  tid);
    stage(w + B_IN,  A.in[3], 4,  tid);
    stage(w + W_OUT, A.in[6], 4,  tid);
    stage(w + B_OUT, A.in[7], 1,  tid);
    stage(w + QKV_W, A.in[10], 48, tid);
    stage(w + QKV_B, A.in[11], 12, tid);
    stage(w + O_W,   A.in[12], 16, tid);
    stage(w + O_B,   A.in[13], 4,  tid);
    stage(w + LN1G,  A.in[14], 4,  tid);
    stage(w + LN1B,  A.in[15], 4,  tid);
    stage(w + FF1W,  A.in[16], 64, tid);
    stage(w + FF1B,  A.in[17], 16, tid);
    stage(w + FF2W,  A.in[18], 64, tid);
    stage(w + FF2B,  A.in[19], 4,  tid);
    stage(w + LN2G,  A.in[20], 4, tid);
    stage(w + LN2B,  A.in[21], 4, tid);

    const float* xinI = A.in[0] + batch * IMG_;
    float tokI[4];
#pragma unroll
    for (int qq = 0; qq < 4; qq++) tokI[qq] = xinI[tid + 256 * qq];

    double mI[13];
#pragma unroll
    for (int k = 0; k < 13; k++) mI[k] = 0.0;
#pragma unroll
    for (int qq = 0; qq < 4; qq++) {
      const double x = (double)tokI[qq];
      double px = x;
#pragma unroll
      for (int k = 0; k < 13; k++) { mI[k] += px; px *= x; }
    }
#pragma unroll
    for (int k = 0; k < 13; k++) mI[k] = wave_sum_d(mI[k]);
    if ((tid & 63) == 0) {
      const int wv = tid >> 6;
#pragma unroll
      for (int k = 0; k < 13; k++) mws[wv][k] = mI[k];
    }
    __syncthreads();             // covers w restage AND mws
    float MfI[14];
    MfI[0] = (float)IMG_;
#pragma unroll
    for (int k = 0; k < 13; k++)
      MfI[k + 1] = (float)(mws[0][k] + mws[1][k] + mws[2][k] + mws[3][k]);

    for (int qq = 0; qq < 4; qq++) {
      const float outv = row_tail(w, tokI[qq], MfI);
      const float* wc = A.in[34] + 3 * (qq * 256 + tid);
      float a0 = outv * wc[0], a1 = outv * wc[1], a2 = outv * wc[2];
#pragma unroll
      for (int msk = 1; msk < 64; msk <<= 1) {
        a0 += __shfl_xor(a0, msk); a1 += __shfl_xor(a1, msk); a2 += __shfl_xor(a2, msk);
      }
      if ((tid & 63) == 0) {
        const int wv = tid >> 6;
        red[wv][0] = a0; red[wv][1] = a1; red[wv][2] = a2;
      }
      __syncthreads();
#pragma unroll
      for (int c = 0; c < 3; c++)
        sq[qq][c] = red[0][c] + red[1][c] + red[2][c] + red[3][c];
      __syncthreads();           // before next qq overwrites red
    }
  }

  if (tid == 0) {
    const float* bc = A.in[35];
    float z[3];
#pragma unroll
    for (int c = 0; c < 3; c++) {
      float s = bc[c];
      if (fb) {
#pragma unroll
        for (int i = 0; i < 4; i++) s += sq[i][c];            // winner order
      } else {
#pragma unroll
        for (int i = 0; i < 4; i++) s += vals[i * 3 + c];     // winner order
      }
      s += (c == 0) ? si0 : (c == 1) ? si1 : si2;             // own ind partial
      z[c] = s;
    }
    const float mx = fmaxf(z[0], fmaxf(z[1], z[2]));
    const float e0 = __expf(z[0] - mx), e1 = __expf(z[1] - mx), e2 = __expf(z[2] - mx);
    const float rs = 1.f / (e0 + e1 + e2);
    A.out[batch * 3 + 0] = e0 * rs;
    A.out[batch * 3 + 1] = e1 * rs;
    A.out[batch * 3 + 2] = e2 * rs;
  }
}

extern "C" void kernel_launch(void* const* d_in, const int* in_sizes, int n_in,
                              void* d_out, int out_size, void* d_ws, size_t ws_size,
                              hipStream_t stream) {
  KArgs A;
  for (int i = 0; i < 36; i++) A.in[i] = (const float*)d_in[i];
  A.pout = (unsigned long long*)d_ws;   // 768 u64 slots, self-validating
  A.out  = (float*)d_out;

  fused<<<NBLK, NTHR, 0, stream>>>(A);
}